// Round 1
// 1224.001 us; speedup vs baseline: 1.0725x; 1.0725x over previous
//
#include <hip/hip_runtime.h>

// ---------------- problem constants ----------------
#define DDIM 1024          // model dim (K of gemm1, N of gemm2)
#define FDIM 2752          // ffn dim
#define FP   2816          // F padded to 22*128 (zero-padded weights -> no N/K guards)
#define TTOK 8192          // tokens
#define SH_OFF 17408       // routed list capacity (16384 + 8*128 align pad), 128-aligned
#define NA   25600         // SH_OFF + TTOK total assignment rows (h rows)

typedef unsigned short u16;
typedef short bf16x8 __attribute__((ext_vector_type(8)));
typedef float f32x4 __attribute__((ext_vector_type(4)));

__device__ __forceinline__ u16 f2b(float f) {
  unsigned u = __float_as_uint(f);
  u += 0x7fff + ((u >> 16) & 1);   // round-to-nearest-even
  return (u16)(u >> 16);
}

__device__ __forceinline__ float b2f(u16 b) {
  return __uint_as_float(((unsigned)b) << 16);
}

// async global->LDS, 16B per lane. LDS dest is wave-uniform base + lane*16.
__device__ __forceinline__ void async16(const void* g, void* s) {
  __builtin_amdgcn_global_load_lds((const __attribute__((address_space(1))) void*)g,
                                   (__attribute__((address_space(3))) void*)s, 16, 0, 0);
}

// ctrl layout (ints): [0..7] counts, [8..15] cursors, [16..24] off[9], [25] nrb_routed, [26] nrb_total

// ---------------- router: 1 wave per token ----------------
__global__ void router_kernel(const float* __restrict__ x, const float* __restrict__ rw,
                              const float* __restrict__ rb, int* __restrict__ topk_id,
                              float* __restrict__ topk_w, int* __restrict__ ctrl) {
  const int wv = threadIdx.x >> 6, lane = threadIdx.x & 63;
  const int t = blockIdx.x * 4 + wv;
  const float* xr = x + (size_t)t * DDIM;
  float acc[8];
#pragma unroll
  for (int e = 0; e < 8; e++) acc[e] = 0.f;
  for (int d = lane; d < DDIM; d += 64) {
    float xv = xr[d];
    const float4* w4 = (const float4*)(rw + (size_t)d * 8);
    float4 wa = w4[0], wb = w4[1];
    acc[0] += xv * wa.x; acc[1] += xv * wa.y; acc[2] += xv * wa.z; acc[3] += xv * wa.w;
    acc[4] += xv * wb.x; acc[5] += xv * wb.y; acc[6] += xv * wb.z; acc[7] += xv * wb.w;
  }
#pragma unroll
  for (int e = 0; e < 8; e++)
    for (int o = 32; o > 0; o >>= 1) acc[e] += __shfl_xor(acc[e], o, 64);
  if (lane == 0) {
    float l[8];
#pragma unroll
    for (int e = 0; e < 8; e++) l[e] = acc[e] + rb[e];
    int i1 = 0; float b1 = l[0];
#pragma unroll
    for (int e = 1; e < 8; e++) if (l[e] > b1) { b1 = l[e]; i1 = e; }
    int i2 = -1; float b2 = -3.4e38f;
#pragma unroll
    for (int e = 0; e < 8; e++) if (e != i1 && l[e] > b2) { b2 = l[e]; i2 = e; }
    // renormalized top-2 softmax weights: w1 = sigmoid(l1-l2)
    float w1 = 1.f / (1.f + __expf(b2 - b1));
    topk_id[2 * t] = i1; topk_id[2 * t + 1] = i2;
    topk_w[2 * t] = w1;  topk_w[2 * t + 1] = 1.f - w1;
    atomicAdd(&ctrl[i1], 1); atomicAdd(&ctrl[i2], 1);
  }
}

// ---------------- offsets + row-block map (single thread, ~200 iters) ----------------
__global__ void build_kernel(int* __restrict__ ctrl, int2* __restrict__ bmap) {
  if (threadIdx.x != 0 || blockIdx.x != 0) return;
  int o = 0, nrb = 0;
  for (int e = 0; e < 8; e++) {
    ctrl[16 + e] = o;
    int c = ctrl[e];
    int nb = (c + 127) >> 7;
    for (int i = 0; i < nb; i++) bmap[nrb++] = make_int2(o + i * 128, e);
    o += nb * 128;            // 128-aligned segments; o <= 17400 < SH_OFF
  }
  ctrl[25] = nrb;             // routed blocks (<=135)
  ctrl[16 + 8] = SH_OFF;
  for (int i = 0; i < 64; i++) bmap[nrb++] = make_int2(SH_OFF + i * 128, 8);
  ctrl[26] = nrb;             // total (<=199)
}

// ---------------- scatter token ids/weights into per-expert segments ----------------
// also builds the inverse map inv[2t+k] = assignment row of token t's k-th expert
__global__ void fill_kernel(const int* __restrict__ topk_id, const float* __restrict__ topk_w,
                            int* __restrict__ ctrl, int* __restrict__ tok, float* __restrict__ tw,
                            int* __restrict__ inv) {
  int t = blockIdx.x * 256 + threadIdx.x;
  if (t >= TTOK) return;
#pragma unroll
  for (int k = 0; k < 2; k++) {
    int e = topk_id[2 * t + k];
    int pos = atomicAdd(&ctrl[8 + e], 1);
    int idx = ctrl[16 + e] + pos;
    tok[idx] = t; tw[idx] = topk_w[2 * t + k];
    inv[2 * t + k] = idx;
  }
  tok[SH_OFF + t] = t; tw[SH_OFF + t] = 1.0f;
}

// ---------------- x fp32 -> bf16 ----------------
__global__ void cvt_x(const float* __restrict__ x, u16* __restrict__ xb) {
  size_t i = ((size_t)blockIdx.x * 256 + threadIdx.x) * 4;
  float4 v = *(const float4*)(x + i);
  ushort4 o;
  o.x = f2b(v.x); o.y = f2b(v.y); o.z = f2b(v.z); o.w = f2b(v.w);
  *(ushort4*)(xb + i) = o;
}

// ---------------- transpose+cast: out[c][r] = in[r][c] (0 outside R/C) ----------------
// out dims [Cp][Rp] row-major. grid (Rp/64, Cp/64, 9); z==8 uses the shared-expert tensor.
__global__ void transpose_cvt(const float* __restrict__ inE, const float* __restrict__ inSh,
                              u16* __restrict__ out, int R, int C, int Cp, int Rp) {
  const float* in = (blockIdx.z < 8) ? inE + (size_t)blockIdx.z * R * C : inSh;
  u16* o = out + (size_t)blockIdx.z * Cp * Rp;
  __shared__ float tile[64 * 65];
  int r0 = blockIdx.x * 64, c0 = blockIdx.y * 64;
#pragma unroll
  for (int i = 0; i < 16; i++) {
    int idx = threadIdx.x + 256 * i;
    int ri = idx >> 6, ci = idx & 63;
    int r = r0 + ri, c = c0 + ci;
    float v = 0.f;
    if (r < R && c < C) v = in[(size_t)r * C + c];
    tile[ci * 65 + ri] = v;
  }
  __syncthreads();
#pragma unroll
  for (int i = 0; i < 16; i++) {
    int idx = threadIdx.x + 256 * i;
    int co = idx >> 6, ro = idx & 63;
    o[(size_t)(c0 + co) * Rp + (r0 + ro)] = f2b(tile[co * 65 + ro]);
  }
}

// LDS tile: logical [128 rows][4 chunks of 16B], linear layout, chunk XOR-swizzled by
// ((row>>1)&3) on BOTH the global source (staging) and the read address (rule #21).
// After swizzle a 16-lane fragment read spans 8 distinct 16B slots -> 2-way (free).

// ---------------- GEMM1: h = silu(Xg)*(Xu), grouped by expert ----------------
// A: gathered token rows of xb [m][k=d], B: wg/wu [9][FP][D] ([n=f][k=d]). 128x128 tile, BK=32.
// 1-D grid, XCD-chunked, N-fastest: each XCD walks 22 consecutive N-tiles sharing one A-tile.
__global__ __launch_bounds__(256, 2)
void gemm_gateup(const u16* __restrict__ xb, const u16* __restrict__ wg, const u16* __restrict__ wu,
                 const int* __restrict__ ctrl, const int2* __restrict__ bmap,
                 const int* __restrict__ tok, u16* __restrict__ h) {
  // bijective XCD-chunk remap: 4400 = 8 * 550
  const int l = blockIdx.x;
  const int w = (l & 7) * 550 + (l >> 3);
  const int rblk = w / 22, n0 = (w % 22) * 128;
  if (rblk >= ctrl[26]) return;
  int2 be = bmap[rblk];
  const int row0 = be.x, e = be.y;

  __shared__ u16 sA[128 * 32];
  __shared__ u16 sBg[128 * 32];
  __shared__ u16 sBu[128 * 32];

  const int tid = threadIdx.x;
  const int ra = tid >> 2;
  const int c16 = (tid & 3) ^ ((ra >> 1) & 3);   // pre-swizzled source chunk
  const int ub0 = (tid & 192) * 8;       // wave-uniform LDS base (ushort units), j=0
  const int ub1 = ub0 + 2048;            // j=1 (+256 chunks * 8 ushorts)

  const u16* a0 = xb + (size_t)tok[row0 + ra] * DDIM + c16 * 8;
  const u16* a1 = xb + (size_t)tok[row0 + 64 + ra] * DDIM + c16 * 8;  // ((ra+64)>>1)&3 == (ra>>1)&3
  const u16* g0 = wg + ((size_t)e * FP + n0 + ra) * DDIM + c16 * 8;
  const u16* g1 = g0 + (size_t)64 * DDIM;
  const u16* u0 = wu + ((size_t)e * FP + n0 + ra) * DDIM + c16 * 8;
  const u16* u1 = u0 + (size_t)64 * DDIM;

  const int lane = tid & 63, wv = tid >> 6;
  const int mb = (wv >> 1) * 64, nb = (wv & 1) * 64;
  const int fr = lane & 15, kq = lane >> 4;
  const int kqs = (kq ^ ((fr >> 1) & 3)) * 8;    // swizzled read chunk (row%16 == fr)

  f32x4 accg[16], accu[16];
#pragma unroll
  for (int i = 0; i < 16; i++) { accg[i] = (f32x4)(0.0f); accu[i] = (f32x4)(0.0f); }

  for (int kk = 0; kk < DDIM; kk += 32) {
    async16(a0 + kk, sA + ub0);
    async16(a1 + kk, sA + ub1);
    async16(g0 + kk, sBg + ub0);
    async16(g1 + kk, sBg + ub1);
    async16(u0 + kk, sBu + ub0);
    async16(u1 + kk, sBu + ub1);
    __syncthreads();
    bf16x8 af[4], bg[4], bu[4];
#pragma unroll
    for (int i = 0; i < 4; i++) {
      af[i] = *(const bf16x8*)(sA + (mb + i * 16 + fr) * 32 + kqs);
      bg[i] = *(const bf16x8*)(sBg + (nb + i * 16 + fr) * 32 + kqs);
      bu[i] = *(const bf16x8*)(sBu + (nb + i * 16 + fr) * 32 + kqs);
    }
#pragma unroll
    for (int mi = 0; mi < 4; mi++)
#pragma unroll
      for (int ni = 0; ni < 4; ni++) {
        accg[mi * 4 + ni] = __builtin_amdgcn_mfma_f32_16x16x32_bf16(af[mi], bg[ni], accg[mi * 4 + ni], 0, 0, 0);
        accu[mi * 4 + ni] = __builtin_amdgcn_mfma_f32_16x16x32_bf16(af[mi], bu[ni], accu[mi * 4 + ni], 0, 0, 0);
      }
    __syncthreads();
  }
  // epilogue: h = silu(g)*u, bf16. C layout: col=lane&15, row=(lane>>4)*4+reg
#pragma unroll
  for (int mi = 0; mi < 4; mi++)
#pragma unroll
    for (int ni = 0; ni < 4; ni++) {
      f32x4 g = accg[mi * 4 + ni], u = accu[mi * 4 + ni];
#pragma unroll
      for (int r = 0; r < 4; r++) {
        float gv = g[r];
        float hv = (gv * u[r]) / (1.0f + __expf(-gv));
        int row = row0 + mb + mi * 16 + kq * 4 + r;
        int col = n0 + nb + ni * 16 + fr;
        h[(size_t)row * FP + col] = f2b(hv);
      }
    }
}

// ---------------- GEMM2a: routed down-projection, plain bf16 stores to hd ----------------
__global__ __launch_bounds__(256, 3)
void gemm_down_r(const u16* __restrict__ h, const u16* __restrict__ wd,
                 const int* __restrict__ ctrl, const int2* __restrict__ bmap,
                 u16* __restrict__ hd) {
  // 1088 = 8 * 136 blocks, XCD-chunked, N-fastest (8 N-tiles per row-block)
  const int l = blockIdx.x;
  const int w = (l & 7) * 136 + (l >> 3);
  const int rblk = w >> 3, n0 = (w & 7) * 128;
  if (rblk >= ctrl[25]) return;
  int2 be = bmap[rblk];
  const int row0 = be.x, e = be.y;

  __shared__ u16 sA[128 * 32];
  __shared__ u16 sB[128 * 32];

  const int tid = threadIdx.x;
  const int ra = tid >> 2;
  const int c16 = (tid & 3) ^ ((ra >> 1) & 3);
  const int ub0 = (tid & 192) * 8, ub1 = ub0 + 2048;

  const u16* a0 = h + (size_t)(row0 + ra) * FP + c16 * 8;
  const u16* a1 = a0 + (size_t)64 * FP;
  const u16* b0 = wd + ((size_t)e * DDIM + n0 + ra) * FP + c16 * 8;
  const u16* b1 = b0 + (size_t)64 * FP;

  const int lane = tid & 63, wv = tid >> 6;
  const int mb = (wv >> 1) * 64, nb = (wv & 1) * 64;
  const int fr = lane & 15, kq = lane >> 4;
  const int kqs = (kq ^ ((fr >> 1) & 3)) * 8;

  f32x4 acc[16];
#pragma unroll
  for (int i = 0; i < 16; i++) acc[i] = (f32x4)(0.0f);

  for (int kk = 0; kk < FP; kk += 32) {
    async16(a0 + kk, sA + ub0);
    async16(a1 + kk, sA + ub1);
    async16(b0 + kk, sB + ub0);
    async16(b1 + kk, sB + ub1);
    __syncthreads();
    bf16x8 af[4], bf[4];
#pragma unroll
    for (int i = 0; i < 4; i++) {
      af[i] = *(const bf16x8*)(sA + (mb + i * 16 + fr) * 32 + kqs);
      bf[i] = *(const bf16x8*)(sB + (nb + i * 16 + fr) * 32 + kqs);
    }
#pragma unroll
    for (int mi = 0; mi < 4; mi++)
#pragma unroll
      for (int ni = 0; ni < 4; ni++)
        acc[mi * 4 + ni] = __builtin_amdgcn_mfma_f32_16x16x32_bf16(af[mi], bf[ni], acc[mi * 4 + ni], 0, 0, 0);
    __syncthreads();
  }

#pragma unroll
  for (int mi = 0; mi < 4; mi++)
#pragma unroll
    for (int r = 0; r < 4; r++) {
      int row = row0 + mb + mi * 16 + kq * 4 + r;    // < SH_OFF
      u16* orow = hd + (size_t)row * DDIM;
#pragma unroll
      for (int ni = 0; ni < 4; ni++) {
        int col = n0 + nb + ni * 16 + fr;
        orow[col] = f2b(acc[mi * 4 + ni][r]);
      }
    }
}

// ---------------- GEMM2b: shared-expert down-projection + fused weighted combine ----------------
// Covers every output element exactly once: out = shared + w1*hd[r1] + w2*hd[r2]
__global__ __launch_bounds__(256, 3)
void gemm_down_s(const u16* __restrict__ h, const u16* __restrict__ wd,
                 const u16* __restrict__ hd, const int* __restrict__ inv,
                 const float* __restrict__ tw, float* __restrict__ out) {
  // 512 = 8 * 64 blocks, XCD-chunked, N-fastest
  const int l = blockIdx.x;
  const int w = (l & 7) * 64 + (l >> 3);
  const int rblk = w >> 3, n0 = (w & 7) * 128;
  const int row0 = SH_OFF + rblk * 128;
  const int e = 8;

  __shared__ u16 sA[128 * 32];
  __shared__ u16 sB[128 * 32];

  const int tid = threadIdx.x;
  const int ra = tid >> 2;
  const int c16 = (tid & 3) ^ ((ra >> 1) & 3);
  const int ub0 = (tid & 192) * 8, ub1 = ub0 + 2048;

  const u16* a0 = h + (size_t)(row0 + ra) * FP + c16 * 8;
  const u16* a1 = a0 + (size_t)64 * FP;
  const u16* b0 = wd + ((size_t)e * DDIM + n0 + ra) * FP + c16 * 8;
  const u16* b1 = b0 + (size_t)64 * FP;

  const int lane = tid & 63, wv = tid >> 6;
  const int mb = (wv >> 1) * 64, nb = (wv & 1) * 64;
  const int fr = lane & 15, kq = lane >> 4;
  const int kqs = (kq ^ ((fr >> 1) & 3)) * 8;

  f32x4 acc[16];
#pragma unroll
  for (int i = 0; i < 16; i++) acc[i] = (f32x4)(0.0f);

  for (int kk = 0; kk < FP; kk += 32) {
    async16(a0 + kk, sA + ub0);
    async16(a1 + kk, sA + ub1);
    async16(b0 + kk, sB + ub0);
    async16(b1 + kk, sB + ub1);
    __syncthreads();
    bf16x8 af[4], bf[4];
#pragma unroll
    for (int i = 0; i < 4; i++) {
      af[i] = *(const bf16x8*)(sA + (mb + i * 16 + fr) * 32 + kqs);
      bf[i] = *(const bf16x8*)(sB + (nb + i * 16 + fr) * 32 + kqs);
    }
#pragma unroll
    for (int mi = 0; mi < 4; mi++)
#pragma unroll
      for (int ni = 0; ni < 4; ni++)
        acc[mi * 4 + ni] = __builtin_amdgcn_mfma_f32_16x16x32_bf16(af[mi], bf[ni], acc[mi * 4 + ni], 0, 0, 0);
    __syncthreads();
  }

#pragma unroll
  for (int mi = 0; mi < 4; mi++)
#pragma unroll
    for (int r = 0; r < 4; r++) {
      int row = row0 + mb + mi * 16 + kq * 4 + r;
      int t = row - SH_OFF;
      int r1 = inv[2 * t], r2 = inv[2 * t + 1];
      float w1 = tw[r1], w2 = tw[r2];
      const u16* p1 = hd + (size_t)r1 * DDIM;
      const u16* p2 = hd + (size_t)r2 * DDIM;
      float* orow = out + (size_t)t * DDIM;
#pragma unroll
      for (int ni = 0; ni < 4; ni++) {
        int col = n0 + nb + ni * 16 + fr;
        orow[col] = acc[mi * 4 + ni][r] + w1 * b2f(p1[col]) + w2 * b2f(p2[col]);
      }
    }
}

// ---------------- host ----------------
extern "C" void kernel_launch(void* const* d_in, const int* in_sizes, int n_in,
                              void* d_out, int out_size, void* d_ws, size_t ws_size,
                              hipStream_t stream) {
  const float* x       = (const float*)d_in[0];
  const float* rw      = (const float*)d_in[1];
  const float* rb      = (const float*)d_in[2];
  const float* gate_w  = (const float*)d_in[3];
  const float* up_w    = (const float*)d_in[4];
  const float* down_w  = (const float*)d_in[5];
  const float* sh_gate = (const float*)d_in[6];
  const float* sh_up   = (const float*)d_in[7];
  const float* sh_down = (const float*)d_in[8];
  float* out = (float*)d_out;
  char* ws = (char*)d_ws;

  // ws layout (bytes)
  const size_t O_CTRL = 0;                       // 64 ints
  const size_t O_BMAP = 256;                     // int2[256]
  const size_t O_TID  = 2304;                    // int[T*2]
  const size_t O_TW   = O_TID + (size_t)TTOK * 2 * 4;
  const size_t O_TOK  = O_TW + (size_t)TTOK * 2 * 4;
  const size_t O_TKW  = O_TOK + (size_t)NA * 4;
  const size_t O_INV  = O_TKW + (size_t)NA * 4;  // int[T*2] inverse map
  const size_t O_ZEND = O_INV + (size_t)TTOK * 2 * 4;  // everything above zeroed
  const size_t O_XB   = (O_ZEND + 255) & ~(size_t)255;
  const size_t O_WG   = O_XB + (size_t)TTOK * DDIM * 2;
  const size_t O_WU   = O_WG + (size_t)9 * FP * DDIM * 2;
  const size_t O_WD   = O_WU + (size_t)9 * FP * DDIM * 2;
  const size_t O_H    = O_WD + (size_t)9 * DDIM * FP * 2;
  const size_t O_HD   = O_H + (size_t)NA * FP * 2;      // bf16 routed partials [SH_OFF][D]

  int*   ctrl = (int*)(ws + O_CTRL);
  int2*  bmap = (int2*)(ws + O_BMAP);
  int*   tid_ = (int*)(ws + O_TID);
  float* tw_  = (float*)(ws + O_TW);
  int*   tok  = (int*)(ws + O_TOK);
  float* tkw  = (float*)(ws + O_TKW);
  int*   inv  = (int*)(ws + O_INV);
  u16*   xb   = (u16*)(ws + O_XB);
  u16*   wg   = (u16*)(ws + O_WG);
  u16*   wu   = (u16*)(ws + O_WU);
  u16*   wd   = (u16*)(ws + O_WD);
  u16*   h    = (u16*)(ws + O_H);
  u16*   hd   = (u16*)(ws + O_HD);

  hipMemsetAsync(ws, 0, O_ZEND, stream);

  cvt_x<<<dim3(TTOK * DDIM / 1024), 256, 0, stream>>>(x, xb);
  // gate/up: in [D][F] -> out [FP][D]
  transpose_cvt<<<dim3(16, 44, 9), 256, 0, stream>>>(gate_w, sh_gate, wg, DDIM, FDIM, FP, DDIM);
  transpose_cvt<<<dim3(16, 44, 9), 256, 0, stream>>>(up_w, sh_up, wu, DDIM, FDIM, FP, DDIM);
  // down: in [F][D] -> out [D][FP]
  transpose_cvt<<<dim3(44, 16, 9), 256, 0, stream>>>(down_w, sh_down, wd, FDIM, DDIM, DDIM, FP);

  router_kernel<<<dim3(TTOK / 4), 256, 0, stream>>>(x, rw, rb, tid_, tw_, ctrl);
  build_kernel<<<dim3(1), 64, 0, stream>>>(ctrl, bmap);
  fill_kernel<<<dim3(TTOK / 256), 256, 0, stream>>>(tid_, tw_, ctrl, tok, tkw, inv);

  gemm_gateup<<<dim3(200 * (FP / 128)), 256, 0, stream>>>(xb, wg, wu, ctrl, bmap, tok, h);
  gemm_down_r<<<dim3(136 * 8), 256, 0, stream>>>(h, wd, ctrl, bmap, hd);
  gemm_down_s<<<dim3(64 * 8), 256, 0, stream>>>(h, wd, hd, inv, tkw, out);
}

// Round 4
// 1175.655 us; speedup vs baseline: 1.1166x; 1.0411x over previous
//
#include <hip/hip_runtime.h>

// ---------------- problem constants ----------------
#define DDIM 1024          // model dim (K of gemm1, N of gemm2)
#define FDIM 2752          // ffn dim
#define FP   2816          // F padded to 22*128 (zero-padded weights -> no N/K guards)
#define TTOK 8192          // tokens
#define SH_OFF 17408       // routed list capacity (16384 + 8*128 align pad), 128-aligned
#define NA   25600         // SH_OFF + TTOK total assignment rows (h rows)

typedef unsigned short u16;
typedef short bf16x8 __attribute__((ext_vector_type(8)));
typedef float f32x4 __attribute__((ext_vector_type(4)));

__device__ __forceinline__ u16 f2b(float f) {
  unsigned u = __float_as_uint(f);
  u += 0x7fff + ((u >> 16) & 1);   // round-to-nearest-even
  return (u16)(u >> 16);
}

__device__ __forceinline__ float b2f(u16 b) {
  return __uint_as_float(((unsigned)b) << 16);
}

// async global->LDS, 16B per lane. LDS dest is wave-uniform base + lane*16.
__device__ __forceinline__ void async16(const void* g, void* s) {
  __builtin_amdgcn_global_load_lds((const __attribute__((address_space(1))) void*)g,
                                   (__attribute__((address_space(3))) void*)s, 16, 0, 0);
}

// ctrl layout (ints): [0..7] counts, [8..15] cursors, [16..24] off[9], [25] nrb_routed, [26] nrb_total

// ---------------- router: 1 wave per token ----------------
__global__ void router_kernel(const float* __restrict__ x, const float* __restrict__ rw,
                              const float* __restrict__ rb, int* __restrict__ topk_id,
                              float* __restrict__ topk_w, int* __restrict__ ctrl) {
  const int wv = threadIdx.x >> 6, lane = threadIdx.x & 63;
  const int t = blockIdx.x * 4 + wv;
  const float* xr = x + (size_t)t * DDIM;
  float acc[8];
#pragma unroll
  for (int e = 0; e < 8; e++) acc[e] = 0.f;
  for (int d = lane; d < DDIM; d += 64) {
    float xv = xr[d];
    const float4* w4 = (const float4*)(rw + (size_t)d * 8);
    float4 wa = w4[0], wb = w4[1];
    acc[0] += xv * wa.x; acc[1] += xv * wa.y; acc[2] += xv * wa.z; acc[3] += xv * wa.w;
    acc[4] += xv * wb.x; acc[5] += xv * wb.y; acc[6] += xv * wb.z; acc[7] += xv * wb.w;
  }
#pragma unroll
  for (int e = 0; e < 8; e++)
    for (int o = 32; o > 0; o >>= 1) acc[e] += __shfl_xor(acc[e], o, 64);
  if (lane == 0) {
    float l[8];
#pragma unroll
    for (int e = 0; e < 8; e++) l[e] = acc[e] + rb[e];
    int i1 = 0; float b1 = l[0];
#pragma unroll
    for (int e = 1; e < 8; e++) if (l[e] > b1) { b1 = l[e]; i1 = e; }
    int i2 = -1; float b2 = -3.4e38f;
#pragma unroll
    for (int e = 0; e < 8; e++) if (e != i1 && l[e] > b2) { b2 = l[e]; i2 = e; }
    // renormalized top-2 softmax weights: w1 = sigmoid(l1-l2)
    float w1 = 1.f / (1.f + __expf(b2 - b1));
    topk_id[2 * t] = i1; topk_id[2 * t + 1] = i2;
    topk_w[2 * t] = w1;  topk_w[2 * t + 1] = 1.f - w1;
    atomicAdd(&ctrl[i1], 1); atomicAdd(&ctrl[i2], 1);
  }
}

// ---------------- offsets + row-block map (single thread, ~200 iters) ----------------
__global__ void build_kernel(int* __restrict__ ctrl, int2* __restrict__ bmap) {
  if (threadIdx.x != 0 || blockIdx.x != 0) return;
  int o = 0, nrb = 0;
  for (int e = 0; e < 8; e++) {
    ctrl[16 + e] = o;
    int c = ctrl[e];
    int nb = (c + 127) >> 7;
    for (int i = 0; i < nb; i++) bmap[nrb++] = make_int2(o + i * 128, e);
    o += nb * 128;            // 128-aligned segments; o <= 17400 < SH_OFF
  }
  ctrl[25] = nrb;             // routed blocks (<=136)
  ctrl[16 + 8] = SH_OFF;
  for (int i = 0; i < 64; i++) bmap[nrb++] = make_int2(SH_OFF + i * 128, 8);
  ctrl[26] = nrb;             // total (<=200)
}

// ---------------- scatter token ids/weights into per-expert segments ----------------
// also builds the inverse map inv[2t+k] = assignment row of token t's k-th expert
__global__ void fill_kernel(const int* __restrict__ topk_id, const float* __restrict__ topk_w,
                            int* __restrict__ ctrl, int* __restrict__ tok, float* __restrict__ tw,
                            int* __restrict__ inv) {
  int t = blockIdx.x * 256 + threadIdx.x;
  if (t >= TTOK) return;
#pragma unroll
  for (int k = 0; k < 2; k++) {
    int e = topk_id[2 * t + k];
    int pos = atomicAdd(&ctrl[8 + e], 1);
    int idx = ctrl[16 + e] + pos;
    tok[idx] = t; tw[idx] = topk_w[2 * t + k];
    inv[2 * t + k] = idx;
  }
  tok[SH_OFF + t] = t; tw[SH_OFF + t] = 1.0f;
}

// ---------------- x fp32 -> bf16 ----------------
__global__ void cvt_x(const float* __restrict__ x, u16* __restrict__ xb) {
  size_t i = ((size_t)blockIdx.x * 256 + threadIdx.x) * 4;
  float4 v = *(const float4*)(x + i);
  ushort4 o;
  o.x = f2b(v.x); o.y = f2b(v.y); o.z = f2b(v.z); o.w = f2b(v.w);
  *(ushort4*)(xb + i) = o;
}

// ---------------- transpose+cast: out[c][r] = in[r][c] (0 outside R/C) ----------------
// out dims [Cp][Rp] row-major. grid (Rp/64, Cp/64, 9); z==8 uses the shared-expert tensor.
// float4 global loads, ushort4 global stores; +65 pad keeps LDS at 2-way (free).
__global__ void transpose_cvt(const float* __restrict__ inE, const float* __restrict__ inSh,
                              u16* __restrict__ out, int R, int C, int Cp, int Rp) {
  const float* in = (blockIdx.z < 8) ? inE + (size_t)blockIdx.z * R * C : inSh;
  u16* o = out + (size_t)blockIdx.z * Cp * Rp;
  __shared__ float tile[64 * 65];
  int r0 = blockIdx.x * 64, c0 = blockIdx.y * 64;
#pragma unroll
  for (int i = 0; i < 4; i++) {
    int idx = threadIdx.x + 256 * i;           // 0..1023
    int ri = idx >> 4, c4 = (idx & 15) * 4;    // row 0..63, col 0..60 step 4
    int r = r0 + ri, c = c0 + c4;
    float4 v = make_float4(0.f, 0.f, 0.f, 0.f);
    if (r < R && c < C) v = *(const float4*)(in + (size_t)r * C + c);  // C%4==0 -> full vec in range
    tile[(c4 + 0) * 65 + ri] = v.x;
    tile[(c4 + 1) * 65 + ri] = v.y;
    tile[(c4 + 2) * 65 + ri] = v.z;
    tile[(c4 + 3) * 65 + ri] = v.w;
  }
  __syncthreads();
#pragma unroll
  for (int i = 0; i < 4; i++) {
    int idx = threadIdx.x + 256 * i;
    int co = idx >> 4, ro4 = (idx & 15) * 4;
    ushort4 s;
    s.x = f2b(tile[co * 65 + ro4 + 0]);
    s.y = f2b(tile[co * 65 + ro4 + 1]);
    s.z = f2b(tile[co * 65 + ro4 + 2]);
    s.w = f2b(tile[co * 65 + ro4 + 3]);
    *(ushort4*)(o + (size_t)(c0 + co) * Rp + (r0 + ro4)) = s;
  }
}

// ==================================================================================
// Counted-vmcnt GEMMs: 512 threads (8 waves, 2M x 4N), BM=128, BN=256, BK=32,
// triple-buffered LDS, prefetch 2 K-tiles ahead, vmcnt never drained to 0 in the
// main loop, setprio around MFMA clusters, raw s_barrier + lgkmcnt(0)+sched_barrier(0).
// LDS chunk XOR-swizzle: chunk slot s of row r holds K-chunk s XOR ((r>>1)&3);
// applied on the global SOURCE at staging and on the READ address (both-sides rule).
// Stage identity: dest u16 offset = tid*8 = row(tid>>2)*32 + slot(tid&3)*8.
// ==================================================================================

// ---------------- GEMM1: h = silu(Xg)*(Xu), grouped by expert ----------------
// LDS buffer (u16 units): A[0,4096) Bg[4096,12288) Bu[12288,20480); 3 bufs = 122880 B.
__global__ __launch_bounds__(512, 2)
void gemm_gateup(const u16* __restrict__ xb, const u16* __restrict__ wg, const u16* __restrict__ wu,
                 const int* __restrict__ ctrl, const int2* __restrict__ bmap,
                 const int* __restrict__ tok, u16* __restrict__ h) {
  // XCD owns 25 consecutive rblk; n0-outer, rblk-inner.
  const int xcd = blockIdx.x & 7, i = blockIdx.x >> 3;     // i 0..274
  const int n0 = (i / 25) * 256;                           // 11 values: 0..2560
  const int rblk = xcd * 25 + (i % 25);                    // 0..199
  if (rblk >= ctrl[26]) return;
  int2 be = bmap[rblk];
  const int row0 = be.x, e = be.y;

  extern __shared__ u16 sm[];                              // 3 * 20480 u16

  const int tid = threadIdx.x;
  const int wvb = (tid >> 6) * 512;                        // wave-uniform LDS offset (u16)
  const int ra = tid >> 2;                                 // 0..127
  const int ca = (tid & 3) ^ ((ra >> 1) & 3);              // pre-swizzled source chunk
  const u16* pA  = xb + (size_t)tok[row0 + ra] * DDIM + ca * 8;
  const u16* pG0 = wg + ((size_t)e * FP + n0 + ra) * DDIM + ca * 8;   // B rows 0..127
  const u16* pG1 = pG0 + (size_t)128 * DDIM;                          // B rows 128..255 (same swz)
  const u16* pU0 = wu + ((size_t)e * FP + n0 + ra) * DDIM + ca * 8;
  const u16* pU1 = pU0 + (size_t)128 * DDIM;

  const int lane = tid & 63, wv = tid >> 6;
  const int wm = wv >> 2, wn = wv & 3;                     // 2M x 4N waves, 64x64 each
  const int fr = lane & 15, kq = lane >> 4;
  const int kqs8 = (kq ^ ((fr >> 1) & 3)) * 8;             // swizzled read chunk

  f32x4 accg[16], accu[16];
#pragma unroll
  for (int q = 0; q < 16; q++) { accg[q] = (f32x4)(0.0f); accu[q] = (f32x4)(0.0f); }

  // prologue: stage t=0 -> buf0, t=1 -> buf1 (5 loads each, in order)
  async16(pA,        sm + 0     + wvb);
  async16(pG0,       sm + 4096  + wvb);
  async16(pG1,       sm + 8192  + wvb);
  async16(pU0,       sm + 12288 + wvb);
  async16(pU1,       sm + 16384 + wvb);
  async16(pA  + 32,  sm + 20480 + 0     + wvb);
  async16(pG0 + 32,  sm + 20480 + 4096  + wvb);
  async16(pG1 + 32,  sm + 20480 + 8192  + wvb);
  async16(pU0 + 32,  sm + 20480 + 12288 + wvb);
  async16(pU1 + 32,  sm + 20480 + 16384 + wvb);
  asm volatile("s_waitcnt vmcnt(5)" ::: "memory");         // t0's 5 landed; t1 in flight
  __builtin_amdgcn_s_barrier();

  int pC = 0, pN = 20480, pS = 40960;                      // compute / next / stage bases
  for (int t = 0; t < 32; ++t) {
    const int t2 = t + 2;
    bf16x8 a[4], bg[4], bu[4];
    // ---- phase G: ds-read A+Bg, stage 3 of t+2, 16 gate-MFMA ----
#pragma unroll
    for (int mi = 0; mi < 4; mi++)
      a[mi] = *(const bf16x8*)(sm + pC + (wm * 64 + mi * 16 + fr) * 32 + kqs8);
#pragma unroll
    for (int ni = 0; ni < 4; ni++)
      bg[ni] = *(const bf16x8*)(sm + pC + 4096 + (wn * 64 + ni * 16 + fr) * 32 + kqs8);
    if (t2 < 32) {
      async16(pA  + t2 * 32, sm + pS + wvb);
      async16(pG0 + t2 * 32, sm + pS + 4096 + wvb);
      async16(pG1 + t2 * 32, sm + pS + 8192 + wvb);
    }
    __builtin_amdgcn_s_barrier();
    asm volatile("s_waitcnt lgkmcnt(0)" ::: "memory");
    __builtin_amdgcn_sched_barrier(0);
    __builtin_amdgcn_s_setprio(1);
#pragma unroll
    for (int mi = 0; mi < 4; mi++)
#pragma unroll
      for (int ni = 0; ni < 4; ni++)
        accg[mi * 4 + ni] = __builtin_amdgcn_mfma_f32_16x16x32_bf16(a[mi], bg[ni], accg[mi * 4 + ni], 0, 0, 0);
    __builtin_amdgcn_s_setprio(0);
    __builtin_amdgcn_s_barrier();
    // ---- phase U: ds-read Bu, stage 2 of t+2, 16 up-MFMA ----
#pragma unroll
    for (int ni = 0; ni < 4; ni++)
      bu[ni] = *(const bf16x8*)(sm + pC + 12288 + (wn * 64 + ni * 16 + fr) * 32 + kqs8);
    if (t2 < 32) {
      async16(pU0 + t2 * 32, sm + pS + 12288 + wvb);
      async16(pU1 + t2 * 32, sm + pS + 16384 + wvb);
    }
    __builtin_amdgcn_s_barrier();
    asm volatile("s_waitcnt lgkmcnt(0)" ::: "memory");
    __builtin_amdgcn_sched_barrier(0);
    __builtin_amdgcn_s_setprio(1);
#pragma unroll
    for (int mi = 0; mi < 4; mi++)
#pragma unroll
      for (int ni = 0; ni < 4; ni++)
        accu[mi * 4 + ni] = __builtin_amdgcn_mfma_f32_16x16x32_bf16(a[mi], bu[ni], accu[mi * 4 + ni], 0, 0, 0);
    __builtin_amdgcn_s_setprio(0);
    if (t2 < 32) asm volatile("s_waitcnt vmcnt(5)" ::: "memory");   // retire t+1's 5 loads
    else         asm volatile("s_waitcnt vmcnt(0)" ::: "memory");   // drain tail
    __builtin_amdgcn_s_barrier();
    int tmp = pC; pC = pN; pN = pS; pS = tmp;
  }

  // epilogue: h = silu(g)*u, bf16. C layout: col=lane&15, row=(lane>>4)*4+reg
#pragma unroll
  for (int mi = 0; mi < 4; mi++)
#pragma unroll
    for (int ni = 0; ni < 4; ni++) {
      f32x4 g = accg[mi * 4 + ni], u = accu[mi * 4 + ni];
#pragma unroll
      for (int r = 0; r < 4; r++) {
        float gv = g[r];
        float hv = (gv * u[r]) / (1.0f + __expf(-gv));
        int row = row0 + wm * 64 + mi * 16 + kq * 4 + r;
        int col = n0 + wn * 64 + ni * 16 + fr;
        h[(size_t)row * FP + col] = f2b(hv);
      }
    }
}

// ---------------- GEMM2a: routed down-projection, plain bf16 stores to hd ----------------
// LDS buffer (u16 units): A[0,4096) B[4096,12288); 3 bufs = 73728 B. NT = 88.
__global__ __launch_bounds__(512, 2)
void gemm_down_r(const u16* __restrict__ h, const u16* __restrict__ wd,
                 const int* __restrict__ ctrl, const int2* __restrict__ bmap,
                 u16* __restrict__ hd) {
  const int xcd = blockIdx.x & 7, i = blockIdx.x >> 3;     // i 0..67
  const int n0 = (i / 17) * 256;                           // 4 values
  const int rblk = xcd * 17 + (i % 17);                    // 0..135
  if (rblk >= ctrl[25]) return;
  int2 be = bmap[rblk];
  const int row0 = be.x, e = be.y;

  extern __shared__ u16 sm[];

  const int tid = threadIdx.x;
  const int wvb = (tid >> 6) * 512;
  const int ra = tid >> 2;
  const int ca = (tid & 3) ^ ((ra >> 1) & 3);
  const u16* pA  = h + (size_t)(row0 + ra) * FP + ca * 8;
  const u16* pB0 = wd + ((size_t)e * DDIM + n0 + ra) * FP + ca * 8;
  const u16* pB1 = pB0 + (size_t)128 * FP;

  const int lane = tid & 63, wv = tid >> 6;
  const int wm = wv >> 2, wn = wv & 3;
  const int fr = lane & 15, kq = lane >> 4;
  const int kqs8 = (kq ^ ((fr >> 1) & 3)) * 8;

  f32x4 acc[16];
#pragma unroll
  for (int q = 0; q < 16; q++) acc[q] = (f32x4)(0.0f);

  async16(pA,       sm + 0     + wvb);
  async16(pB0,      sm + 4096  + wvb);
  async16(pB1,      sm + 8192  + wvb);
  async16(pA  + 32, sm + 12288 + 0    + wvb);
  async16(pB0 + 32, sm + 12288 + 4096 + wvb);
  async16(pB1 + 32, sm + 12288 + 8192 + wvb);
  asm volatile("s_waitcnt vmcnt(3)" ::: "memory");
  __builtin_amdgcn_s_barrier();

  int pC = 0, pN = 12288, pS = 24576;
  for (int t = 0; t < 88; ++t) {
    const int t2 = t + 2;
    bf16x8 a[4], bb[4];
#pragma unroll
    for (int mi = 0; mi < 4; mi++)
      a[mi] = *(const bf16x8*)(sm + pC + (wm * 64 + mi * 16 + fr) * 32 + kqs8);
#pragma unroll
    for (int ni = 0; ni < 4; ni++)
      bb[ni] = *(const bf16x8*)(sm + pC + 4096 + (wn * 64 + ni * 16 + fr) * 32 + kqs8);
    if (t2 < 88) {
      async16(pA  + t2 * 32, sm + pS + wvb);
      async16(pB0 + t2 * 32, sm + pS + 4096 + wvb);
      async16(pB1 + t2 * 32, sm + pS + 8192 + wvb);
    }
    __builtin_amdgcn_s_barrier();
    asm volatile("s_waitcnt lgkmcnt(0)" ::: "memory");
    __builtin_amdgcn_sched_barrier(0);
    __builtin_amdgcn_s_setprio(1);
#pragma unroll
    for (int mi = 0; mi < 4; mi++)
#pragma unroll
      for (int ni = 0; ni < 4; ni++)
        acc[mi * 4 + ni] = __builtin_amdgcn_mfma_f32_16x16x32_bf16(a[mi], bb[ni], acc[mi * 4 + ni], 0, 0, 0);
    __builtin_amdgcn_s_setprio(0);
    if (t2 < 88) asm volatile("s_waitcnt vmcnt(3)" ::: "memory");
    else         asm volatile("s_waitcnt vmcnt(0)" ::: "memory");
    __builtin_amdgcn_s_barrier();
    int tmp = pC; pC = pN; pN = pS; pS = tmp;
  }

#pragma unroll
  for (int mi = 0; mi < 4; mi++)
#pragma unroll
    for (int r = 0; r < 4; r++) {
      int row = row0 + wm * 64 + mi * 16 + kq * 4 + r;     // < SH_OFF
      u16* orow = hd + (size_t)row * DDIM;
#pragma unroll
      for (int ni = 0; ni < 4; ni++) {
        int col = n0 + wn * 64 + ni * 16 + fr;
        orow[col] = f2b(acc[mi * 4 + ni][r]);
      }
    }
}

// ---------------- GEMM2b: shared-expert down-projection + fused weighted combine ----------------
// Covers every output element exactly once: out = shared + w1*hd[r1] + w2*hd[r2]
__global__ __launch_bounds__(512, 2)
void gemm_down_s(const u16* __restrict__ h, const u16* __restrict__ wd,
                 const u16* __restrict__ hd, const int* __restrict__ inv,
                 const float* __restrict__ tw, float* __restrict__ out) {
  const int xcd = blockIdx.x & 7, i = blockIdx.x >> 3;     // i 0..31
  const int n0 = (i / 8) * 256;
  const int rblk = xcd * 8 + (i % 8);                      // 0..63
  const int row0 = SH_OFF + rblk * 128;
  const int e = 8;

  extern __shared__ u16 sm[];

  const int tid = threadIdx.x;
  const int wvb = (tid >> 6) * 512;
  const int ra = tid >> 2;
  const int ca = (tid & 3) ^ ((ra >> 1) & 3);
  const u16* pA  = h + (size_t)(row0 + ra) * FP + ca * 8;
  const u16* pB0 = wd + ((size_t)e * DDIM + n0 + ra) * FP + ca * 8;
  const u16* pB1 = pB0 + (size_t)128 * FP;

  const int lane = tid & 63, wv = tid >> 6;
  const int wm = wv >> 2, wn = wv & 3;
  const int fr = lane & 15, kq = lane >> 4;
  const int kqs8 = (kq ^ ((fr >> 1) & 3)) * 8;

  f32x4 acc[16];
#pragma unroll
  for (int q = 0; q < 16; q++) acc[q] = (f32x4)(0.0f);

  async16(pA,       sm + 0     + wvb);
  async16(pB0,      sm + 4096  + wvb);
  async16(pB1,      sm + 8192  + wvb);
  async16(pA  + 32, sm + 12288 + 0    + wvb);
  async16(pB0 + 32, sm + 12288 + 4096 + wvb);
  async16(pB1 + 32, sm + 12288 + 8192 + wvb);
  asm volatile("s_waitcnt vmcnt(3)" ::: "memory");
  __builtin_amdgcn_s_barrier();

  int pC = 0, pN = 12288, pS = 24576;
  for (int t = 0; t < 88; ++t) {
    const int t2 = t + 2;
    bf16x8 a[4], bb[4];
#pragma unroll
    for (int mi = 0; mi < 4; mi++)
      a[mi] = *(const bf16x8*)(sm + pC + (wm * 64 + mi * 16 + fr) * 32 + kqs8);
#pragma unroll
    for (int ni = 0; ni < 4; ni++)
      bb[ni] = *(const bf16x8*)(sm + pC + 4096 + (wn * 64 + ni * 16 + fr) * 32 + kqs8);
    if (t2 < 88) {
      async16(pA  + t2 * 32, sm + pS + wvb);
      async16(pB0 + t2 * 32, sm + pS + 4096 + wvb);
      async16(pB1 + t2 * 32, sm + pS + 8192 + wvb);
    }
    __builtin_amdgcn_s_barrier();
    asm volatile("s_waitcnt lgkmcnt(0)" ::: "memory");
    __builtin_amdgcn_sched_barrier(0);
    __builtin_amdgcn_s_setprio(1);
#pragma unroll
    for (int mi = 0; mi < 4; mi++)
#pragma unroll
      for (int ni = 0; ni < 4; ni++)
        acc[mi * 4 + ni] = __builtin_amdgcn_mfma_f32_16x16x32_bf16(a[mi], bb[ni], acc[mi * 4 + ni], 0, 0, 0);
    __builtin_amdgcn_s_setprio(0);
    if (t2 < 88) asm volatile("s_waitcnt vmcnt(3)" ::: "memory");
    else         asm volatile("s_waitcnt vmcnt(0)" ::: "memory");
    __builtin_amdgcn_s_barrier();
    int tmp = pC; pC = pN; pN = pS; pS = tmp;
  }

#pragma unroll
  for (int mi = 0; mi < 4; mi++)
#pragma unroll
    for (int r = 0; r < 4; r++) {
      int row = row0 + wm * 64 + mi * 16 + kq * 4 + r;
      int t = row - SH_OFF;
      int r1 = inv[2 * t], r2 = inv[2 * t + 1];
      float w1 = tw[r1], w2 = tw[r2];
      const u16* p1 = hd + (size_t)r1 * DDIM;
      const u16* p2 = hd + (size_t)r2 * DDIM;
      float* orow = out + (size_t)t * DDIM;
#pragma unroll
      for (int ni = 0; ni < 4; ni++) {
        int col = n0 + wn * 64 + ni * 16 + fr;
        orow[col] = acc[mi * 4 + ni][r] + w1 * b2f(p1[col]) + w2 * b2f(p2[col]);
      }
    }
}

// ---------------- host ----------------
extern "C" void kernel_launch(void* const* d_in, const int* in_sizes, int n_in,
                              void* d_out, int out_size, void* d_ws, size_t ws_size,
                              hipStream_t stream) {
  const float* x       = (const float*)d_in[0];
  const float* rw      = (const float*)d_in[1];
  const float* rb      = (const float*)d_in[2];
  const float* gate_w  = (const float*)d_in[3];
  const float* up_w    = (const float*)d_in[4];
  const float* down_w  = (const float*)d_in[5];
  const float* sh_gate = (const float*)d_in[6];
  const float* sh_up   = (const float*)d_in[7];
  const float* sh_down = (const float*)d_in[8];
  float* out = (float*)d_out;
  char* ws = (char*)d_ws;

  // ws layout (bytes)
  const size_t O_CTRL = 0;                       // 64 ints
  const size_t O_BMAP = 256;                     // int2[256]
  const size_t O_TID  = 2304;                    // int[T*2]
  const size_t O_TW   = O_TID + (size_t)TTOK * 2 * 4;
  const size_t O_TOK  = O_TW + (size_t)TTOK * 2 * 4;
  const size_t O_TKW  = O_TOK + (size_t)NA * 4;
  const size_t O_INV  = O_TKW + (size_t)NA * 4;  // int[T*2] inverse map
  const size_t O_ZEND = O_INV + (size_t)TTOK * 2 * 4;  // everything above zeroed
  const size_t O_XB   = (O_ZEND + 255) & ~(size_t)255;
  const size_t O_WG   = O_XB + (size_t)TTOK * DDIM * 2;
  const size_t O_WU   = O_WG + (size_t)9 * FP * DDIM * 2;
  const size_t O_WD   = O_WU + (size_t)9 * FP * DDIM * 2;
  const size_t O_H    = O_WD + (size_t)9 * DDIM * FP * 2;
  const size_t O_HD   = O_H + (size_t)NA * FP * 2;      // bf16 routed partials [SH_OFF][D]

  int*   ctrl = (int*)(ws + O_CTRL);
  int2*  bmap = (int2*)(ws + O_BMAP);
  int*   tid_ = (int*)(ws + O_TID);
  float* tw_  = (float*)(ws + O_TW);
  int*   tok  = (int*)(ws + O_TOK);
  float* tkw  = (float*)(ws + O_TKW);
  int*   inv  = (int*)(ws + O_INV);
  u16*   xb   = (u16*)(ws + O_XB);
  u16*   wg   = (u16*)(ws + O_WG);
  u16*   wu   = (u16*)(ws + O_WU);
  u16*   wd   = (u16*)(ws + O_WD);
  u16*   h    = (u16*)(ws + O_H);
  u16*   hd   = (u16*)(ws + O_HD);

  // opt-in to >64KiB dynamic LDS
  hipFuncSetAttribute((const void*)gemm_gateup, hipFuncAttributeMaxDynamicSharedMemorySize, 122880);
  hipFuncSetAttribute((const void*)gemm_down_r, hipFuncAttributeMaxDynamicSharedMemorySize, 73728);
  hipFuncSetAttribute((const void*)gemm_down_s, hipFuncAttributeMaxDynamicSharedMemorySize, 73728);

  hipMemsetAsync(ws, 0, O_ZEND, stream);

  cvt_x<<<dim3(TTOK * DDIM / 1024), 256, 0, stream>>>(x, xb);
  // gate/up: in [D][F] -> out [FP][D]
  transpose_cvt<<<dim3(16, 44, 9), 256, 0, stream>>>(gate_w, sh_gate, wg, DDIM, FDIM, FP, DDIM);
  transpose_cvt<<<dim3(16, 44, 9), 256, 0, stream>>>(up_w, sh_up, wu, DDIM, FDIM, FP, DDIM);
  // down: in [F][D] -> out [D][FP]
  transpose_cvt<<<dim3(44, 16, 9), 256, 0, stream>>>(down_w, sh_down, wd, FDIM, DDIM, DDIM, FP);

  router_kernel<<<dim3(TTOK / 4), 256, 0, stream>>>(x, rw, rb, tid_, tw_, ctrl);
  build_kernel<<<dim3(1), 64, 0, stream>>>(ctrl, bmap);
  fill_kernel<<<dim3(TTOK / 256), 256, 0, stream>>>(tid_, tw_, ctrl, tok, tkw, inv);

  gemm_gateup<<<dim3(8 * 275), 512, 122880, stream>>>(xb, wg, wu, ctrl, bmap, tok, h);
  gemm_down_r<<<dim3(8 * 68), 512, 73728, stream>>>(h, wd, ctrl, bmap, hd);
  gemm_down_s<<<dim3(8 * 32), 512, 73728, stream>>>(h, wd, hd, inv, tkw, out);
}